// Round 2
// baseline (1050.598 us; speedup 1.0000x reference)
//
#include <hip/hip_runtime.h>

#define Bb 8
#define Nn 20000
#define Cc 128
#define Kk 64
#define Ee 320000

#define WAVES_PER_BLOCK 4
#define NODES_PER_WAVE 4

// ---------------------------------------------------------------------------
// Kernel 1: per-node MLP -> softmax -> mask  => S (B,N,K) f32
// wave-per-quad-of-nodes; W1 (32KB) + W2 (16KB) staged in LDS.
// ---------------------------------------------------------------------------
__global__ __launch_bounds__(256) void k_compute_S(
    const float* __restrict__ x, const int* __restrict__ mask,
    const float* __restrict__ W1, const float* __restrict__ b1,
    const float* __restrict__ W2, const float* __restrict__ b2,
    float* __restrict__ S)
{
    __shared__ float W1s[Cc * Kk];                                  // 32 KB
    __shared__ float W2s[Kk * Kk];                                  // 16 KB
    __shared__ __align__(16) float xs[WAVES_PER_BLOCK][NODES_PER_WAVE * Cc]; // 8 KB
    __shared__ __align__(16) float hs[WAVES_PER_BLOCK][NODES_PER_WAVE * Kk]; // 4 KB

    const int tid = threadIdx.x;
    for (int i = tid; i < Cc * Kk; i += 256) W1s[i] = W1[i];
    for (int i = tid; i < Kk * Kk; i += 256) W2s[i] = W2[i];
    __syncthreads();

    const int lane = tid & 63;
    const int wid  = tid >> 6;
    const float b1k = b1[lane];
    const float b2l = b2[lane];

    const int quadsPerBatch = Nn / NODES_PER_WAVE;        // 5000
    const int totalQuads = Bb * quadsPerBatch;            // 40000
    const int gwave  = blockIdx.x * WAVES_PER_BLOCK + wid;
    const int nwaves = gridDim.x * WAVES_PER_BLOCK;

    for (int q = gwave; q < totalQuads; q += nwaves) {
        const int b  = q / quadsPerBatch;
        const int n0 = (q % quadsPerBatch) * NODES_PER_WAVE;
        const size_t xbase = ((size_t)b * Nn + n0) * Cc;

        // stage 4 node rows of x (512 contiguous floats) into this wave's LDS
        {
            const float4* xg = (const float4*)(x + xbase);
            float4* xl = (float4*)xs[wid];
            #pragma unroll
            for (int i = 0; i < 2; ++i) xl[lane + 64 * i] = xg[lane + 64 * i];
        }

        // h = relu(x @ W1 + b1); lane owns column k=lane, 4 nodes at once
        float h[NODES_PER_WAVE];
        #pragma unroll
        for (int i = 0; i < NODES_PER_WAVE; ++i) h[i] = b1k;

        for (int c0 = 0; c0 < Cc; c0 += 4) {
            float4 xv[NODES_PER_WAVE];
            #pragma unroll
            for (int i = 0; i < NODES_PER_WAVE; ++i)
                xv[i] = *(const float4*)&xs[wid][i * Cc + c0];
            #pragma unroll
            for (int j = 0; j < 4; ++j) {
                const float w1 = W1s[(c0 + j) * Kk + lane];
                #pragma unroll
                for (int i = 0; i < NODES_PER_WAVE; ++i) {
                    const float xj = (j == 0) ? xv[i].x : (j == 1) ? xv[i].y
                                    : (j == 2) ? xv[i].z : xv[i].w;
                    h[i] = fmaf(xj, w1, h[i]);
                }
            }
        }
        #pragma unroll
        for (int i = 0; i < NODES_PER_WAVE; ++i)
            hs[wid][i * Kk + lane] = fmaxf(h[i], 0.f);

        // logits = h @ W2 + b2; lane owns column l=lane
        float a[NODES_PER_WAVE];
        #pragma unroll
        for (int i = 0; i < NODES_PER_WAVE; ++i) a[i] = b2l;

        for (int k0 = 0; k0 < Kk; k0 += 4) {
            float4 hv[NODES_PER_WAVE];
            #pragma unroll
            for (int i = 0; i < NODES_PER_WAVE; ++i)
                hv[i] = *(const float4*)&hs[wid][i * Kk + k0];
            #pragma unroll
            for (int j = 0; j < 4; ++j) {
                const float w2 = W2s[(k0 + j) * Kk + lane];
                #pragma unroll
                for (int i = 0; i < NODES_PER_WAVE; ++i) {
                    const float hj = (j == 0) ? hv[i].x : (j == 1) ? hv[i].y
                                    : (j == 2) ? hv[i].z : hv[i].w;
                    a[i] = fmaf(hj, w2, a[i]);
                }
            }
        }

        // softmax over the 64 lanes (K dim), apply node mask, store S row
        #pragma unroll
        for (int i = 0; i < NODES_PER_WAVE; ++i) {
            float mx = a[i];
            #pragma unroll
            for (int off = 32; off >= 1; off >>= 1)
                mx = fmaxf(mx, __shfl_xor(mx, off));
            const float e = __expf(a[i] - mx);
            float sm = e;
            #pragma unroll
            for (int off = 32; off >= 1; off >>= 1)
                sm += __shfl_xor(sm, off);
            const float mv = (mask[(size_t)b * Nn + n0 + i] > 0) ? 1.f : 0.f;
            S[((size_t)b * Nn + n0 + i) * Kk + lane] = e / sm * mv;
        }
    }
}

// ---------------------------------------------------------------------------
// Kernel 2: pmask (B,K) — 1 iff any mask>0 in the batch row
// ---------------------------------------------------------------------------
__global__ __launch_bounds__(256) void k_pmask(const int* __restrict__ mask,
                                               float* __restrict__ pmask)
{
    __shared__ int s_any;
    if (threadIdx.x == 0) s_any = 0;
    __syncthreads();
    const int b = blockIdx.x;
    int any = 0;
    for (int i = threadIdx.x; i < Nn; i += blockDim.x)
        any |= (mask[(size_t)b * Nn + i] > 0) ? 1 : 0;
    if (any) atomicOr(&s_any, 1);
    __syncthreads();
    if (threadIdx.x < Kk)
        pmask[(size_t)b * Kk + threadIdx.x] = s_any ? 1.f : 0.f;
}

// ---------------------------------------------------------------------------
// Kernel 3 (fused): pooled_adj[b,k,l] = sum_e w_e * S[b,v_e,k] * S[b,u_e,l]
// (identity: mid[v] += w*S[u]; pooled = S^T mid  ==  sum_e w * S[v] outer S[u])
// wave-per-64-edge-group, ballot-compact valid edges, rank-1 update into
// per-lane register column acc[64]; LDS block reduce; global atomic flush.
// Edges with m[u]==0 (S[u]=0) or m[v]==0 (S[v]=0) contribute nothing -> skip.
// ---------------------------------------------------------------------------
__global__ __launch_bounds__(256) void k_pooled_edges(
    const int* __restrict__ ei, const float* __restrict__ ew,
    const int* __restrict__ mask, const float* __restrict__ S,
    float* __restrict__ pooled)
{
    __shared__ float tile[Kk * Kk];   // 16 KB
    const int tid  = threadIdx.x;
    const int lane = tid & 63;
    const int wid  = tid >> 6;

    for (int i = tid; i < Kk * Kk; i += 256) tile[i] = 0.f;
    __syncthreads();

    const int b    = blockIdx.x >> 6;          // 64 blocks per batch
    const int slot = blockIdx.x & 63;
    const int groupsPerBatch = Ee / 64;        // 5000
    const size_t eib = (size_t)b * 2 * Ee;
    const float* Sb  = S + (size_t)b * Nn * Kk;
    const int*   mb  = mask + (size_t)b * Nn;

    float acc[Kk];
    #pragma unroll
    for (int k = 0; k < Kk; ++k) acc[k] = 0.f;

    for (int g = slot * WAVES_PER_BLOCK + wid; g < groupsPerBatch; g += 64 * WAVES_PER_BLOCK) {
        const int e0 = g * 64;
        const int   u = ei[eib + e0 + lane];           // int32 on device!
        const int   v = ei[eib + Ee + e0 + lane];
        const float w = ew[(size_t)b * Ee + e0 + lane];
        const bool valid = (mb[u] > 0) && (mb[v] > 0) && (w != 0.f);

        unsigned long long vm = __ballot(valid);
        while (vm) {
            const int t = __builtin_ctzll(vm);
            vm &= vm - 1;
            const int   ut = __shfl(u, t);
            const int   vt = __shfl(v, t);
            const float wt = __shfl(w, t);
            const float su = Sb[(size_t)ut * Kk + lane];   // column l = lane
            const float sv = Sb[(size_t)vt * Kk + lane];   // row source, broadcast below
            const float wsu = wt * su;
            #pragma unroll
            for (int k = 0; k < Kk; ++k)
                acc[k] = fmaf(__shfl(sv, k), wsu, acc[k]);
        }
    }

    // block reduce: 4 waves -> LDS tile (row k, col lane)
    #pragma unroll
    for (int k = 0; k < Kk; ++k)
        atomicAdd(&tile[k * Kk + lane], acc[k]);
    __syncthreads();

    float* pb = pooled + (size_t)b * Kk * Kk;
    for (int i = tid; i < Kk * Kk; i += 256)
        atomicAdd(&pb[i], tile[i]);
}

// ---------------------------------------------------------------------------
// Kernel 4: pfeat[b,k,c] = sum_n S[b,n,k] * x[b,n,c]
// thread owns (k, 32 c's) in registers; 8-node LDS staging; atomic epilogue
// ---------------------------------------------------------------------------
#define PF_NODES 8
__global__ __launch_bounds__(256) void k_pfeat(
    const float* __restrict__ x, const float* __restrict__ S,
    float* __restrict__ pfeat)
{
    __shared__ __align__(16) float xsh[PF_NODES * Cc];  // 4 KB
    __shared__ __align__(16) float ssh[PF_NODES * Kk];  // 2 KB
    const int tid = threadIdx.x;
    const int k   = tid & 63;
    const int c0  = (tid >> 6) * 32;
    const int b   = blockIdx.x & 7;
    const int bslot = blockIdx.x >> 3;
    const int blocksPerBatch = gridDim.x >> 3;
    const int chunks = Nn / PF_NODES;                    // 2500

    float acc[32];
    #pragma unroll
    for (int j = 0; j < 32; ++j) acc[j] = 0.f;

    for (int ch = bslot; ch < chunks; ch += blocksPerBatch) {
        const size_t nb = (size_t)b * Nn + (size_t)ch * PF_NODES;
        __syncthreads();
        {
            const float4* xg = (const float4*)(x + nb * Cc);
            const float4* sg = (const float4*)(S + nb * Kk);
            float4* xl = (float4*)xsh;
            float4* sl = (float4*)ssh;
            xl[tid] = xg[tid];                           // 256 float4 = 8*128
            if (tid < 128) sl[tid] = sg[tid];            // 128 float4 = 8*64
        }
        __syncthreads();
        #pragma unroll
        for (int nn = 0; nn < PF_NODES; ++nn) {
            const float s = ssh[nn * Kk + k];
            #pragma unroll
            for (int j4 = 0; j4 < 8; ++j4) {
                const float4 xv = *(const float4*)&xsh[nn * Cc + c0 + j4 * 4];
                acc[j4 * 4 + 0] = fmaf(s, xv.x, acc[j4 * 4 + 0]);
                acc[j4 * 4 + 1] = fmaf(s, xv.y, acc[j4 * 4 + 1]);
                acc[j4 * 4 + 2] = fmaf(s, xv.z, acc[j4 * 4 + 2]);
                acc[j4 * 4 + 3] = fmaf(s, xv.w, acc[j4 * 4 + 3]);
            }
        }
    }
    float* pf = pfeat + (size_t)b * Kk * Cc + (size_t)k * Cc + c0;
    #pragma unroll
    for (int j = 0; j < 32; ++j) atomicAdd(&pf[j], acc[j]);
}

// ---------------------------------------------------------------------------
extern "C" void kernel_launch(void* const* d_in, const int* in_sizes, int n_in,
                              void* d_out, int out_size, void* d_ws, size_t ws_size,
                              hipStream_t stream)
{
    const float* x    = (const float*)d_in[0];
    const int*   ei   = (const int*)d_in[1];     // int64 in reference -> int32 on device
    const float* ew   = (const float*)d_in[2];
    const int*   mask = (const int*)d_in[3];
    const float* W1   = (const float*)d_in[4];
    const float* b1   = (const float*)d_in[5];
    const float* W2   = (const float*)d_in[6];
    const float* b2   = (const float*)d_in[7];

    float* out    = (float*)d_out;
    float* pfeat  = out;                                               // B*K*C
    float* pooled = out + (size_t)Bb * Kk * Cc;                        // B*K*K
    float* pmask  = out + (size_t)Bb * Kk * Cc + (size_t)Bb * Kk * Kk; // B*K

    float* S = (float*)d_ws;                                           // B*N*K f32 = 40.96 MB

    hipMemsetAsync(d_out, 0, sizeof(float) * (size_t)out_size, stream);

    k_compute_S<<<1024, 256, 0, stream>>>(x, mask, W1, b1, W2, b2, S);
    k_pmask<<<Bb, 256, 0, stream>>>(mask, pmask);
    k_pooled_edges<<<512, 256, 0, stream>>>(ei, ew, mask, S, pooled);
    k_pfeat<<<512, 256, 0, stream>>>(x, S, pfeat);
}